// Round 1
// baseline (819.407 us; speedup 1.0000x reference)
//
#include <hip/hip_runtime.h>
#include <hip/hip_bf16.h>
#include <math.h>

// Problem shapes (fixed by setup_inputs):
//   feats:  (6,256,64,120) (6,256,32,60) (6,256,16,30) (6,256,8,15)  fp32
//   reference_points (1,3,128,128) fp32, homography (6,4,4) fp32,
//   bev_range (6) fp32, orig_h=512, orig_w=960 (int scalars)
// Outputs (concatenated flat, fp32):
//   bev_feats (6, 1024, 128, 128)   -> 100663296 elems
//   masks     (1, 24, 128, 128)     -> 393216 elems  (order: v, l, h, w)

#define NPOS_PER_LV (128 * 128)       // h*w
#define NPOS_LV (6 * NPOS_PER_LV)     // per level (v,h,w)
#define NPOS_TOTAL (4 * NPOS_LV)      // 393216
#define BEV_ELEMS (6 * 1024 * 128 * 128)

// ---------------------------------------------------------------------------
// Kernel 1: per-(level, view, h, w) projection -> gather offsets + weights.
// Also writes the mask output.
// ---------------------------------------------------------------------------
__global__ __launch_bounds__(256) void precompute_kernel(
    const float* __restrict__ rp,     // (3,128,128)
    const float* __restrict__ homo,   // (6,4,4)
    const float* __restrict__ br,     // (6)
    const int* __restrict__ oh_p,
    const int* __restrict__ ow_p,
    int4* __restrict__ ws_idx,        // [l][v][h][w]
    float4* __restrict__ ws_w,        // [l][v][h][w]
    float* __restrict__ mask_out)     // d_out + BEV_ELEMS, layout (v,l,h,w)
{
    int idx = blockIdx.x * 256 + threadIdx.x;   // < NPOS_TOTAL
    int w = idx & 127;
    int h = (idx >> 7) & 127;
    int lv = idx >> 14;                         // 0..23, = l*6 + v
    int l = lv / 6;
    int v = lv - 6 * l;

    const int HFS[4] = {64, 32, 16, 8};
    const int WFS[4] = {120, 60, 30, 15};
    int Hf = HFS[l], Wf = WFS[l];
    float oh = (float)oh_p[0], ow = (float)ow_p[0];
    float sh = (float)Hf / oh;
    float sw = (float)Wf / ow;

    // ref3d point
    float p[3];
#pragma unroll
    for (int k = 0; k < 3; ++k) {
        float x = rp[k * NPOS_PER_LV + h * 128 + w];
        float s = 1.0f / (1.0f + expf(-x));
        p[k] = s * (br[3 + k] - br[k]) + br[k];
    }

    const float* Hm = homo + v * 16;
    float c0 = sw * (Hm[0] * p[0] + Hm[1] * p[1] + Hm[2]  * p[2] + Hm[3]);
    float c1 = sh * (Hm[4] * p[0] + Hm[5] * p[1] + Hm[6]  * p[2] + Hm[7]);
    float c2 =      (Hm[8] * p[0] + Hm[9] * p[1] + Hm[10] * p[2] + Hm[11]);
    float z = fmaxf(c2, 0.05f);
    float X = c0 / z;
    float Y = c1 / z;

    // mask (uses unclamped X,Y)
    float m = (X >= 0.0f && X < (float)Wf && Y >= 0.0f && Y < (float)Hf) ? 1.0f : 0.0f;
    mask_out[((v * 4 + l) * 128 + h) * 128 + w] = m;

    float x0 = floorf(X), y0 = floorf(Y);
    float wx = X - x0, wy = Y - y0;
    float x1 = x0 + 1.0f, y1 = y0 + 1.0f;
    float Wm1 = (float)(Wf - 1), Hm1 = (float)(Hf - 1);

    // per-corner validity (matches reference's float comparisons)
    bool v00 = (x0 >= 0.0f) && (x0 <= Wm1) && (y0 >= 0.0f) && (y0 <= Hm1);
    bool v01 = (x1 >= 0.0f) && (x1 <= Wm1) && (y0 >= 0.0f) && (y0 <= Hm1);
    bool v10 = (x0 >= 0.0f) && (x0 <= Wm1) && (y1 >= 0.0f) && (y1 <= Hm1);
    bool v11 = (x1 >= 0.0f) && (x1 <= Wm1) && (y1 >= 0.0f) && (y1 <= Hm1);

    float4 wt;
    wt.x = v00 ? (1.0f - wx) * (1.0f - wy) : 0.0f;
    wt.y = v01 ? wx * (1.0f - wy) : 0.0f;
    wt.z = v10 ? (1.0f - wx) * wy : 0.0f;
    wt.w = v11 ? wx * wy : 0.0f;

    // clamped integer indices -> flat offsets within one (Hf,Wf) plane
    int xi0 = (int)fminf(fmaxf(x0, 0.0f), Wm1);
    int xi1 = (int)fminf(fmaxf(x1, 0.0f), Wm1);
    int yi0 = (int)fminf(fmaxf(y0, 0.0f), Hm1);
    int yi1 = (int)fminf(fmaxf(y1, 0.0f), Hm1);

    int4 off;
    off.x = yi0 * Wf + xi0;
    off.y = yi0 * Wf + xi1;
    off.z = yi1 * Wf + xi0;
    off.w = yi1 * Wf + xi1;

    ws_idx[idx] = off;
    ws_w[idx] = wt;
}

// ---------------------------------------------------------------------------
// Kernel 2 (per level): one block per (v,h); each thread owns one (w, c-parity)
// and loops all 128 of its channels with gather offsets/weights in registers.
// ---------------------------------------------------------------------------
__global__ __launch_bounds__(256) void sample_kernel(
    const float* __restrict__ feat,     // (6,256,Hf,Wf)
    const int4* __restrict__ ws_idx,    // this level's [v][h][w]
    const float4* __restrict__ ws_w,
    float* __restrict__ out,            // d_out base
    int Hf, int Wf, int level)
{
    int t = threadIdx.x;
    int w = t & 127;
    int c0 = t >> 7;                 // 0 or 1: channel parity
    int h = blockIdx.x & 127;
    int v = blockIdx.x >> 7;         // 0..5

    int pos = (v * 128 + h) * 128 + w;
    int4 off = ws_idx[pos];
    float4 wt = ws_w[pos];

    const int plane = Hf * Wf;
    const float* fv = feat + (size_t)v * 256 * plane;
    float* ob = out + (size_t)(v * 1024 + level * 256) * NPOS_PER_LV + h * 128 + w;

    // weights are all >= 0, so sum==0 <=> every corner contributes nothing
    if (wt.x + wt.y + wt.z + wt.w != 0.0f) {
#pragma unroll 4
        for (int i = 0; i < 128; ++i) {
            int c = 2 * i + c0;
            const float* fc = fv + (size_t)c * plane;
            float val = fc[off.x] * wt.x + fc[off.y] * wt.y +
                        fc[off.z] * wt.z + fc[off.w] * wt.w;
            ob[(size_t)c * NPOS_PER_LV] = val;
        }
    } else {
#pragma unroll 8
        for (int i = 0; i < 128; ++i) {
            int c = 2 * i + c0;
            ob[(size_t)c * NPOS_PER_LV] = 0.0f;
        }
    }
}

extern "C" void kernel_launch(void* const* d_in, const int* in_sizes, int n_in,
                              void* d_out, int out_size, void* d_ws, size_t ws_size,
                              hipStream_t stream) {
    const float* feats[4] = {(const float*)d_in[0], (const float*)d_in[1],
                             (const float*)d_in[2], (const float*)d_in[3]};
    const float* rp   = (const float*)d_in[4];
    const float* homo = (const float*)d_in[5];
    const float* br   = (const float*)d_in[6];
    const int* oh_p   = (const int*)d_in[7];
    const int* ow_p   = (const int*)d_in[8];

    float* out = (float*)d_out;
    int4*   ws_idx = (int4*)d_ws;
    float4* ws_w   = (float4*)((char*)d_ws + (size_t)NPOS_TOTAL * sizeof(int4));
    float* mask_out = out + (size_t)BEV_ELEMS;

    precompute_kernel<<<NPOS_TOTAL / 256, 256, 0, stream>>>(
        rp, homo, br, oh_p, ow_p, ws_idx, ws_w, mask_out);

    const int HFS[4] = {64, 32, 16, 8};
    const int WFS[4] = {120, 60, 30, 15};
    for (int l = 0; l < 4; ++l) {
        sample_kernel<<<6 * 128, 256, 0, stream>>>(
            feats[l], ws_idx + (size_t)l * NPOS_LV, ws_w + (size_t)l * NPOS_LV,
            out, HFS[l], WFS[l], l);
    }
}

// Round 2
// 532.240 us; speedup vs baseline: 1.5395x; 1.5395x over previous
//
#include <hip/hip_runtime.h>
#include <hip/hip_bf16.h>
#include <math.h>

// Problem shapes (fixed by setup_inputs):
//   feats:  (6,256,64,120) (6,256,32,60) (6,256,16,30) (6,256,8,15)  fp32
//   reference_points (1,3,128,128) fp32, homography (6,4,4) fp32,
//   bev_range (6) fp32, orig_h=512, orig_w=960 (int scalars)
// Outputs (concatenated flat, fp32):
//   bev_feats (6, 1024, 128, 128)   -> 100663296 elems
//   masks     (1, 24, 128, 128)     -> 393216 elems  (order: v, l, h, w)

#define NPOS_PER_LV (128 * 128)       // h*w
#define NPOS_LV (6 * NPOS_PER_LV)     // per level (v,h,w)
#define NPOS_TOTAL (4 * NPOS_LV)      // 393216
#define BEV_ELEMS (6 * 1024 * 128 * 128)

// feature spatial sizes per level
__constant__ int c_dummy; // (unused; keep compiler happy)

// ---------------------------------------------------------------------------
// Kernel 1: per-(level, view, h, w) projection -> gather offsets + weights.
// Also writes the mask output. (unchanged from round 1 — verified correct)
// ---------------------------------------------------------------------------
__global__ __launch_bounds__(256) void precompute_kernel(
    const float* __restrict__ rp,     // (3,128,128)
    const float* __restrict__ homo,   // (6,4,4)
    const float* __restrict__ br,     // (6)
    const int* __restrict__ oh_p,
    const int* __restrict__ ow_p,
    int4* __restrict__ ws_idx,        // [l][v][h][w]
    float4* __restrict__ ws_w,        // [l][v][h][w]
    float* __restrict__ mask_out)     // d_out + BEV_ELEMS, layout (v,l,h,w)
{
    int idx = blockIdx.x * 256 + threadIdx.x;   // < NPOS_TOTAL
    int w = idx & 127;
    int h = (idx >> 7) & 127;
    int lv = idx >> 14;                         // 0..23, = l*6 + v
    int l = lv / 6;
    int v = lv - 6 * l;

    const int HFS[4] = {64, 32, 16, 8};
    const int WFS[4] = {120, 60, 30, 15};
    int Hf = HFS[l], Wf = WFS[l];
    float oh = (float)oh_p[0], ow = (float)ow_p[0];
    float sh = (float)Hf / oh;
    float sw = (float)Wf / ow;

    float p[3];
#pragma unroll
    for (int k = 0; k < 3; ++k) {
        float x = rp[k * NPOS_PER_LV + h * 128 + w];
        float s = 1.0f / (1.0f + expf(-x));
        p[k] = s * (br[3 + k] - br[k]) + br[k];
    }

    const float* Hm = homo + v * 16;
    float c0 = sw * (Hm[0] * p[0] + Hm[1] * p[1] + Hm[2]  * p[2] + Hm[3]);
    float c1 = sh * (Hm[4] * p[0] + Hm[5] * p[1] + Hm[6]  * p[2] + Hm[7]);
    float c2 =      (Hm[8] * p[0] + Hm[9] * p[1] + Hm[10] * p[2] + Hm[11]);
    float z = fmaxf(c2, 0.05f);
    float X = c0 / z;
    float Y = c1 / z;

    float m = (X >= 0.0f && X < (float)Wf && Y >= 0.0f && Y < (float)Hf) ? 1.0f : 0.0f;
    mask_out[((v * 4 + l) * 128 + h) * 128 + w] = m;

    float x0 = floorf(X), y0 = floorf(Y);
    float wx = X - x0, wy = Y - y0;
    float x1 = x0 + 1.0f, y1 = y0 + 1.0f;
    float Wm1 = (float)(Wf - 1), Hm1 = (float)(Hf - 1);

    bool v00 = (x0 >= 0.0f) && (x0 <= Wm1) && (y0 >= 0.0f) && (y0 <= Hm1);
    bool v01 = (x1 >= 0.0f) && (x1 <= Wm1) && (y0 >= 0.0f) && (y0 <= Hm1);
    bool v10 = (x0 >= 0.0f) && (x0 <= Wm1) && (y1 >= 0.0f) && (y1 <= Hm1);
    bool v11 = (x1 >= 0.0f) && (x1 <= Wm1) && (y1 >= 0.0f) && (y1 <= Hm1);

    float4 wt;
    wt.x = v00 ? (1.0f - wx) * (1.0f - wy) : 0.0f;
    wt.y = v01 ? wx * (1.0f - wy) : 0.0f;
    wt.z = v10 ? (1.0f - wx) * wy : 0.0f;
    wt.w = v11 ? wx * wy : 0.0f;

    int xi0 = (int)fminf(fmaxf(x0, 0.0f), Wm1);
    int xi1 = (int)fminf(fmaxf(x1, 0.0f), Wm1);
    int yi0 = (int)fminf(fmaxf(y0, 0.0f), Hm1);
    int yi1 = (int)fminf(fmaxf(y1, 0.0f), Hm1);

    int4 off;
    off.x = yi0 * Wf + xi0;
    off.y = yi0 * Wf + xi1;
    off.z = yi1 * Wf + xi0;
    off.w = yi1 * Wf + xi1;

    ws_idx[idx] = off;
    ws_w[idx] = wt;
}

// ---------------------------------------------------------------------------
// Kernel T: transpose one level's features (6,256,S) -> (6,S,256) so channel
// becomes the contiguous (coalescable) axis for the gather.
// ---------------------------------------------------------------------------
__global__ __launch_bounds__(256) void transpose_kernel(
    const float* __restrict__ feat,   // [6][256][S]
    float* __restrict__ featT,        // [6][S][256]
    int S)
{
    __shared__ float tile[32][33];    // +1 pad: conflict-free both phases
    int tx = threadIdx.x & 31;
    int ty = threadIdx.x >> 5;        // 0..7
    int s0 = blockIdx.x * 32;
    int c0 = blockIdx.y * 32;
    int v  = blockIdx.z;
    const float* fb = feat + (size_t)v * 256 * S;
    float* tb = featT + (size_t)v * S * 256;

#pragma unroll
    for (int k = 0; k < 4; ++k) {
        int c = c0 + ty + 8 * k;
        int s = s0 + tx;
        tile[ty + 8 * k][tx] = (s < S) ? fb[(size_t)c * S + s] : 0.0f;
    }
    __syncthreads();
#pragma unroll
    for (int k = 0; k < 4; ++k) {
        int s = s0 + ty + 8 * k;
        int c = c0 + tx;
        if (s < S) tb[(size_t)s * 256 + c] = tile[tx][ty + 8 * k];
    }
}

// ---------------------------------------------------------------------------
// Kernel 2 (fast path, per level): block = (v, h, 32-wide w tile).
// Phase A: each wave owns 8 positions; corner channel-vectors are read with
//   fully-coalesced 256B loads (c = lane + 64j) from featT, weighted-summed
//   in registers, parked in a stride-257 LDS tile (conflict-free).
// Phase B: re-map threads to (c, w) and store w-coalesced to the
//   (v, c, h, w) output layout.
// ---------------------------------------------------------------------------
#define TILE_STRIDE 257
__global__ __launch_bounds__(256) void sample_kernel_t(
    const float* __restrict__ featT,    // this level: [v][S][256]
    const int4* __restrict__ ws_idx,    // this level's [v][h][w]
    const float4* __restrict__ ws_w,
    float* __restrict__ out,            // d_out base
    int S, int level)
{
    __shared__ float tile[32 * TILE_STRIDE];   // 32.9 KB
    int tid  = threadIdx.x;
    int wave = tid >> 6;          // 0..3
    int lane = tid & 63;
    int w0 = (blockIdx.x & 3) * 32;
    int h  = (blockIdx.x >> 2) & 127;
    int v  = blockIdx.x >> 9;     // 0..5

    const float* base = featT + (size_t)v * S * 256;

#pragma unroll 2
    for (int i = 0; i < 8; ++i) {
        int p = wave * 8 + i;             // local position 0..31
        int pos = (v * 128 + h) * 128 + (w0 + p);
        int4 off = ws_idx[pos];
        float4 wt = ws_w[pos];
        float acc0 = 0.f, acc1 = 0.f, acc2 = 0.f, acc3 = 0.f;
        if (wt.x + wt.y + wt.z + wt.w != 0.0f) {
            const float* p00 = base + (size_t)off.x * 256;
            const float* p01 = base + (size_t)off.y * 256;
            const float* p10 = base + (size_t)off.z * 256;
            const float* p11 = base + (size_t)off.w * 256;
            int c = lane;
            acc0 = p00[c]       * wt.x + p01[c]       * wt.y + p10[c]       * wt.z + p11[c]       * wt.w;
            acc1 = p00[c + 64]  * wt.x + p01[c + 64]  * wt.y + p10[c + 64]  * wt.z + p11[c + 64]  * wt.w;
            acc2 = p00[c + 128] * wt.x + p01[c + 128] * wt.y + p10[c + 128] * wt.z + p11[c + 128] * wt.w;
            acc3 = p00[c + 192] * wt.x + p01[c + 192] * wt.y + p10[c + 192] * wt.z + p11[c + 192] * wt.w;
        }
        float* tr = tile + p * TILE_STRIDE + lane;
        tr[0]   = acc0;
        tr[64]  = acc1;
        tr[128] = acc2;
        tr[192] = acc3;
    }
    __syncthreads();

    int w  = tid & 31;
    int cb = tid >> 5;            // 0..7
    float* ob = out + (size_t)(v * 1024 + level * 256) * NPOS_PER_LV + h * 128 + w0 + w;
#pragma unroll 4
    for (int c = cb; c < 256; c += 8) {
        ob[(size_t)c * NPOS_PER_LV] = tile[w * TILE_STRIDE + c];
    }
}

// ---------------------------------------------------------------------------
// Fallback sampler (round-1, scattered gather from original layout) — used
// only if ws_size can't hold the transposed features.
// ---------------------------------------------------------------------------
__global__ __launch_bounds__(256) void sample_kernel_gather(
    const float* __restrict__ feat,     // (6,256,Hf,Wf)
    const int4* __restrict__ ws_idx,
    const float4* __restrict__ ws_w,
    float* __restrict__ out,
    int Hf, int Wf, int level)
{
    int t = threadIdx.x;
    int w = t & 127;
    int c0 = t >> 7;
    int h = blockIdx.x & 127;
    int v = blockIdx.x >> 7;

    int pos = (v * 128 + h) * 128 + w;
    int4 off = ws_idx[pos];
    float4 wt = ws_w[pos];

    const int plane = Hf * Wf;
    const float* fv = feat + (size_t)v * 256 * plane;
    float* ob = out + (size_t)(v * 1024 + level * 256) * NPOS_PER_LV + h * 128 + w;

    if (wt.x + wt.y + wt.z + wt.w != 0.0f) {
#pragma unroll 4
        for (int i = 0; i < 128; ++i) {
            int c = 2 * i + c0;
            const float* fc = fv + (size_t)c * plane;
            float val = fc[off.x] * wt.x + fc[off.y] * wt.y +
                        fc[off.z] * wt.z + fc[off.w] * wt.w;
            ob[(size_t)c * NPOS_PER_LV] = val;
        }
    } else {
#pragma unroll 8
        for (int i = 0; i < 128; ++i) {
            int c = 2 * i + c0;
            ob[(size_t)c * NPOS_PER_LV] = 0.0f;
        }
    }
}

extern "C" void kernel_launch(void* const* d_in, const int* in_sizes, int n_in,
                              void* d_out, int out_size, void* d_ws, size_t ws_size,
                              hipStream_t stream) {
    const float* feats[4] = {(const float*)d_in[0], (const float*)d_in[1],
                             (const float*)d_in[2], (const float*)d_in[3]};
    const float* rp   = (const float*)d_in[4];
    const float* homo = (const float*)d_in[5];
    const float* br   = (const float*)d_in[6];
    const int* oh_p   = (const int*)d_in[7];
    const int* ow_p   = (const int*)d_in[8];

    float* out = (float*)d_out;

    // ws layout: [ws_idx 6.29MB][ws_w 6.29MB][featT 62.7MB (fast path only)]
    int4*   ws_idx = (int4*)d_ws;
    float4* ws_w   = (float4*)((char*)d_ws + (size_t)NPOS_TOTAL * sizeof(int4));
    float*  featT  = (float*)((char*)d_ws + (size_t)NPOS_TOTAL * (sizeof(int4) + sizeof(float4)));
    float* mask_out = out + (size_t)BEV_ELEMS;

    const int HFS[4] = {64, 32, 16, 8};
    const int WFS[4] = {120, 60, 30, 15};
    const int SS[4]  = {64 * 120, 32 * 60, 16 * 30, 8 * 15};  // 7680,1920,480,120
    size_t featT_off[4];
    size_t acc = 0;
    for (int l = 0; l < 4; ++l) { featT_off[l] = acc; acc += (size_t)6 * 256 * SS[l]; }
    const size_t WS_NEEDED = (size_t)NPOS_TOTAL * (sizeof(int4) + sizeof(float4))
                           + acc * sizeof(float);             // ~75.3 MB

    precompute_kernel<<<NPOS_TOTAL / 256, 256, 0, stream>>>(
        rp, homo, br, oh_p, ow_p, ws_idx, ws_w, mask_out);

    if (ws_size >= WS_NEEDED) {
        // fast path: transpose each level's features, then coalesced sampling
        for (int l = 0; l < 4; ++l) {
            dim3 grid((SS[l] + 31) / 32, 8, 6);
            transpose_kernel<<<grid, 256, 0, stream>>>(
                feats[l], featT + featT_off[l], SS[l]);
        }
        for (int l = 0; l < 4; ++l) {
            sample_kernel_t<<<6 * 128 * 4, 256, 0, stream>>>(
                featT + featT_off[l],
                ws_idx + (size_t)l * NPOS_LV, ws_w + (size_t)l * NPOS_LV,
                out, SS[l], l);
        }
    } else {
        // fallback: round-1 scattered gather
        for (int l = 0; l < 4; ++l) {
            sample_kernel_gather<<<6 * 128, 256, 0, stream>>>(
                feats[l], ws_idx + (size_t)l * NPOS_LV, ws_w + (size_t)l * NPOS_LV,
                out, HFS[l], WFS[l], l);
        }
    }
}

// Round 4
// 468.647 us; speedup vs baseline: 1.7485x; 1.1357x over previous
//
#include <hip/hip_runtime.h>
#include <hip/hip_bf16.h>
#include <math.h>

// Problem shapes (fixed by setup_inputs):
//   feats:  (6,256,64,120) (6,256,32,60) (6,256,16,30) (6,256,8,15)  fp32
//   reference_points (1,3,128,128) fp32, homography (6,4,4) fp32,
//   bev_range (6) fp32, orig_h=512, orig_w=960 (int scalars)
// Outputs (concatenated flat, fp32):
//   bev_feats (6, 1024, 128, 128)   -> 100663296 elems
//   masks     (1, 24, 128, 128)     -> 393216 elems  (order: v, l, h, w)

#define NPOS_PER_LV (128 * 128)
#define NPOS_LV (6 * NPOS_PER_LV)
#define NPOS_TOTAL (4 * NPOS_LV)
#define BEV_ELEMS (6 * 1024 * 128 * 128)

typedef float floatx4 __attribute__((ext_vector_type(4)));

// ---------------------------------------------------------------------------
// Kernel 1: per-(level, view, h, w) projection -> gather offsets + weights.
// Also writes the mask output. (verified correct rounds 1-2)
// ---------------------------------------------------------------------------
__global__ __launch_bounds__(256) void precompute_kernel(
    const float* __restrict__ rp, const float* __restrict__ homo,
    const float* __restrict__ br, const int* __restrict__ oh_p,
    const int* __restrict__ ow_p, int4* __restrict__ ws_idx,
    float4* __restrict__ ws_w, float* __restrict__ mask_out)
{
    int idx = blockIdx.x * 256 + threadIdx.x;
    int w = idx & 127;
    int h = (idx >> 7) & 127;
    int lv = idx >> 14;
    int l = lv / 6;
    int v = lv - 6 * l;

    const int HFS[4] = {64, 32, 16, 8};
    const int WFS[4] = {120, 60, 30, 15};
    int Hf = HFS[l], Wf = WFS[l];
    float oh = (float)oh_p[0], ow = (float)ow_p[0];
    float sh = (float)Hf / oh;
    float sw = (float)Wf / ow;

    float p[3];
#pragma unroll
    for (int k = 0; k < 3; ++k) {
        float x = rp[k * NPOS_PER_LV + h * 128 + w];
        float s = 1.0f / (1.0f + expf(-x));
        p[k] = s * (br[3 + k] - br[k]) + br[k];
    }

    const float* Hm = homo + v * 16;
    float c0 = sw * (Hm[0] * p[0] + Hm[1] * p[1] + Hm[2]  * p[2] + Hm[3]);
    float c1 = sh * (Hm[4] * p[0] + Hm[5] * p[1] + Hm[6]  * p[2] + Hm[7]);
    float c2 =      (Hm[8] * p[0] + Hm[9] * p[1] + Hm[10] * p[2] + Hm[11]);
    float z = fmaxf(c2, 0.05f);
    float X = c0 / z;
    float Y = c1 / z;

    float m = (X >= 0.0f && X < (float)Wf && Y >= 0.0f && Y < (float)Hf) ? 1.0f : 0.0f;
    mask_out[((v * 4 + l) * 128 + h) * 128 + w] = m;

    float x0 = floorf(X), y0 = floorf(Y);
    float wx = X - x0, wy = Y - y0;
    float x1 = x0 + 1.0f, y1 = y0 + 1.0f;
    float Wm1 = (float)(Wf - 1), Hm1 = (float)(Hf - 1);

    bool v00 = (x0 >= 0.0f) && (x0 <= Wm1) && (y0 >= 0.0f) && (y0 <= Hm1);
    bool v01 = (x1 >= 0.0f) && (x1 <= Wm1) && (y0 >= 0.0f) && (y0 <= Hm1);
    bool v10 = (x0 >= 0.0f) && (x0 <= Wm1) && (y1 >= 0.0f) && (y1 <= Hm1);
    bool v11 = (x1 >= 0.0f) && (x1 <= Wm1) && (y1 >= 0.0f) && (y1 <= Hm1);

    float4 wt;
    wt.x = v00 ? (1.0f - wx) * (1.0f - wy) : 0.0f;
    wt.y = v01 ? wx * (1.0f - wy) : 0.0f;
    wt.z = v10 ? (1.0f - wx) * wy : 0.0f;
    wt.w = v11 ? wx * wy : 0.0f;

    int xi0 = (int)fminf(fmaxf(x0, 0.0f), Wm1);
    int xi1 = (int)fminf(fmaxf(x1, 0.0f), Wm1);
    int yi0 = (int)fminf(fmaxf(y0, 0.0f), Hm1);
    int yi1 = (int)fminf(fmaxf(y1, 0.0f), Hm1);

    int4 off;
    off.x = yi0 * Wf + xi0;
    off.y = yi0 * Wf + xi1;
    off.z = yi1 * Wf + xi0;
    off.w = yi1 * Wf + xi1;

    ws_idx[idx] = off;
    ws_w[idx] = wt;
}

// ---------------------------------------------------------------------------
// Kernel T (fused, all levels): (6,256,S) -> (6,S,256).
// Nontemporal input loads (read exactly once).
// grid = (240+60+15+4 = 319, 8, 6)
// ---------------------------------------------------------------------------
__global__ __launch_bounds__(256) void transpose_all_kernel(
    const float* __restrict__ f0, const float* __restrict__ f1,
    const float* __restrict__ f2, const float* __restrict__ f3,
    float* __restrict__ t0, float* __restrict__ t1,
    float* __restrict__ t2, float* __restrict__ t3)
{
    __shared__ float tile[32][33];
    int bx = blockIdx.x;
    const float* fb; float* tb; int S, sb;
    if (bx < 240)      { fb = f0; tb = t0; S = 7680; sb = bx; }
    else if (bx < 300) { fb = f1; tb = t1; S = 1920; sb = bx - 240; }
    else if (bx < 315) { fb = f2; tb = t2; S = 480;  sb = bx - 300; }
    else               { fb = f3; tb = t3; S = 120;  sb = bx - 315; }
    int v = blockIdx.z;
    int c0 = blockIdx.y * 32;
    int s0 = sb * 32;
    fb += (size_t)v * 256 * S;
    tb += (size_t)v * S * 256;
    int tx = threadIdx.x & 31;
    int ty = threadIdx.x >> 5;

#pragma unroll
    for (int k = 0; k < 4; ++k) {
        int c = c0 + ty + 8 * k;
        int s = s0 + tx;
        tile[ty + 8 * k][tx] =
            (s < S) ? __builtin_nontemporal_load(&fb[(size_t)c * S + s]) : 0.0f;
    }
    __syncthreads();
#pragma unroll
    for (int k = 0; k < 4; ++k) {
        int s = s0 + ty + 8 * k;
        int c = c0 + tx;
        if (s < S) tb[(size_t)s * 256 + c] = tile[tx][ty + 8 * k];
    }
}

// ---------------------------------------------------------------------------
// Kernel 2 (fused, all levels): block = 32-wide w tile of one (l,v,h) row.
// Phase A: wave owns 8 positions; each corner's 256-ch vector read as ONE
//   coalesced 1KB global_load_dwordx4 (float4/lane), weighted-summed, written
//   to a 32KB LDS tile with XOR swizzle (<=2-way banks both phases).
// Phase B: (w4, c)-mapped threads read 4 b32 and emit one nontemporal
//   dwordx4 store (w-contiguous) to the (v, c_total, h, w) output.
// grid = (512, 24): x = h*4 + wtile, y = l*6 + v.
// ---------------------------------------------------------------------------
__global__ __launch_bounds__(256) void sample_all_kernel(
    const float* __restrict__ t0, const float* __restrict__ t1,
    const float* __restrict__ t2, const float* __restrict__ t3,
    const int4* __restrict__ ws_idx,    // [l][v][h][w]
    const float4* __restrict__ ws_w,
    float* __restrict__ out)
{
    __shared__ float tile[32 * 256];    // exactly 32 KB -> 5 blocks/CU
    int tid  = threadIdx.x;
    int wave = tid >> 6;
    int lane = tid & 63;
    int w0 = (blockIdx.x & 3) * 32;
    int h  = blockIdx.x >> 2;
    int lv = blockIdx.y;                // l*6 + v
    int l  = lv / 6;
    int v  = lv - 6 * l;

    const float* base;
    if (l == 0)      base = t0 + (size_t)v * 7680 * 256;
    else if (l == 1) base = t1 + (size_t)v * 1920 * 256;
    else if (l == 2) base = t2 + (size_t)v * 480 * 256;
    else             base = t3 + (size_t)v * 120 * 256;

    int pos_base = lv * NPOS_PER_LV + h * 128 + w0;

#pragma unroll 2
    for (int i = 0; i < 8; ++i) {
        int p = wave * 8 + i;                    // local position 0..31
        int pos = pos_base + p;
        int4 off = ws_idx[pos];
        float4 wt = ws_w[pos];
        float4 acc = {0.f, 0.f, 0.f, 0.f};
        if (wt.x + wt.y + wt.z + wt.w != 0.0f) {
            const float4* p00 = (const float4*)(base + (size_t)off.x * 256);
            const float4* p01 = (const float4*)(base + (size_t)off.y * 256);
            const float4* p10 = (const float4*)(base + (size_t)off.z * 256);
            const float4* p11 = (const float4*)(base + (size_t)off.w * 256);
            float4 f00 = p00[lane];
            float4 f01 = p01[lane];
            float4 f10 = p10[lane];
            float4 f11 = p11[lane];
            acc.x = f00.x * wt.x + f01.x * wt.y + f10.x * wt.z + f11.x * wt.w;
            acc.y = f00.y * wt.x + f01.y * wt.y + f10.y * wt.z + f11.y * wt.w;
            acc.z = f00.z * wt.x + f01.z * wt.y + f10.z * wt.z + f11.z * wt.w;
            acc.w = f00.w * wt.x + f01.w * wt.y + f10.w * wt.z + f11.w * wt.w;
        }
        // swizzled write: word = p*256 + ((4*lane) ^ pat(p)), pat = ((p>>2)&7)<<2
        int pat = ((p >> 2) & 7) << 2;
        *(float4*)&tile[p * 256 + ((4 * lane) ^ pat)] = acc;
    }
    __syncthreads();

    // Phase B: thread -> (w4 = 4*(tid&7), c = (tid>>3) + 32k)
    int w4 = (tid & 7) * 4;
    int cb = tid >> 3;                  // 0..31
    int pat = (tid & 7) << 2;           // = ((p>>2)&7)<<2 for p in [w4, w4+3]
    float* ob = out + (size_t)(v * 1024 + l * 256) * NPOS_PER_LV
                    + h * 128 + w0 + w4;
#pragma unroll
    for (int k = 0; k < 8; ++k) {
        int c = cb + 32 * k;
        int cs = c ^ pat;
        floatx4 val;
        val.x = tile[(w4 + 0) * 256 + cs];
        val.y = tile[(w4 + 1) * 256 + cs];
        val.z = tile[(w4 + 2) * 256 + cs];
        val.w = tile[(w4 + 3) * 256 + cs];
        __builtin_nontemporal_store(val, (floatx4*)(ob + (size_t)c * NPOS_PER_LV));
    }
}

// ---------------------------------------------------------------------------
// Fallback sampler (round-1 style) — only if ws_size can't hold featT.
// ---------------------------------------------------------------------------
__global__ __launch_bounds__(256) void sample_kernel_gather(
    const float* __restrict__ feat, const int4* __restrict__ ws_idx,
    const float4* __restrict__ ws_w, float* __restrict__ out,
    int Hf, int Wf, int level)
{
    int t = threadIdx.x;
    int w = t & 127;
    int c0 = t >> 7;
    int h = blockIdx.x & 127;
    int v = blockIdx.x >> 7;

    int pos = (v * 128 + h) * 128 + w;
    int4 off = ws_idx[pos];
    float4 wt = ws_w[pos];

    const int plane = Hf * Wf;
    const float* fv = feat + (size_t)v * 256 * plane;
    float* ob = out + (size_t)(v * 1024 + level * 256) * NPOS_PER_LV + h * 128 + w;

    if (wt.x + wt.y + wt.z + wt.w != 0.0f) {
#pragma unroll 4
        for (int i = 0; i < 128; ++i) {
            int c = 2 * i + c0;
            const float* fc = fv + (size_t)c * plane;
            float val = fc[off.x] * wt.x + fc[off.y] * wt.y +
                        fc[off.z] * wt.z + fc[off.w] * wt.w;
            ob[(size_t)c * NPOS_PER_LV] = val;
        }
    } else {
#pragma unroll 8
        for (int i = 0; i < 128; ++i) {
            int c = 2 * i + c0;
            ob[(size_t)c * NPOS_PER_LV] = 0.0f;
        }
    }
}

extern "C" void kernel_launch(void* const* d_in, const int* in_sizes, int n_in,
                              void* d_out, int out_size, void* d_ws, size_t ws_size,
                              hipStream_t stream) {
    const float* feats[4] = {(const float*)d_in[0], (const float*)d_in[1],
                             (const float*)d_in[2], (const float*)d_in[3]};
    const float* rp   = (const float*)d_in[4];
    const float* homo = (const float*)d_in[5];
    const float* br   = (const float*)d_in[6];
    const int* oh_p   = (const int*)d_in[7];
    const int* ow_p   = (const int*)d_in[8];

    float* out = (float*)d_out;

    int4*   ws_idx = (int4*)d_ws;
    float4* ws_w   = (float4*)((char*)d_ws + (size_t)NPOS_TOTAL * sizeof(int4));
    float*  featT  = (float*)((char*)d_ws + (size_t)NPOS_TOTAL * (sizeof(int4) + sizeof(float4)));
    float* mask_out = out + (size_t)BEV_ELEMS;

    const int HFS[4] = {64, 32, 16, 8};
    const int WFS[4] = {120, 60, 30, 15};
    const int SS[4]  = {7680, 1920, 480, 120};
    size_t featT_off[4];
    size_t acc = 0;
    for (int l = 0; l < 4; ++l) { featT_off[l] = acc; acc += (size_t)6 * 256 * SS[l]; }
    const size_t WS_NEEDED = (size_t)NPOS_TOTAL * (sizeof(int4) + sizeof(float4))
                           + acc * sizeof(float);             // ~75.5 MB

    precompute_kernel<<<NPOS_TOTAL / 256, 256, 0, stream>>>(
        rp, homo, br, oh_p, ow_p, ws_idx, ws_w, mask_out);

    if (ws_size >= WS_NEEDED) {
        dim3 tgrid(319, 8, 6);
        transpose_all_kernel<<<tgrid, 256, 0, stream>>>(
            feats[0], feats[1], feats[2], feats[3],
            featT + featT_off[0], featT + featT_off[1],
            featT + featT_off[2], featT + featT_off[3]);

        dim3 sgrid(512, 24);
        sample_all_kernel<<<sgrid, 256, 0, stream>>>(
            featT + featT_off[0], featT + featT_off[1],
            featT + featT_off[2], featT + featT_off[3],
            ws_idx, ws_w, out);
    } else {
        for (int l = 0; l < 4; ++l) {
            sample_kernel_gather<<<6 * 128, 256, 0, stream>>>(
                feats[l], ws_idx + (size_t)l * NPOS_LV, ws_w + (size_t)l * NPOS_LV,
                out, HFS[l], WFS[l], l);
        }
    }
}